// Round 12
// baseline (140.110 us; speedup 1.0000x reference)
//
#include <hip/hip_runtime.h>

// out = 0.5 * sum_over_pooled( maxpool4( x @ W^T + b ) )  -> (batch,) fp32
// x: (M=4096, K=2048) f32, W: (N=4096, K=2048) f32, b: (N,) f32, out: (M,) f32
// Strategy: SINGLE kernel. 256x256 BK=64 8-wave MFMA GEMM that reads f32
// directly and converts to bf16 during reg-staging (global f32 -> regs ->
// RNE cvt -> swizzled ds_write_b128) — the separate cvt pass (13-15us of
// pure memory time) is eliminated. R10 schedule: 1 barrier/phase, quadrant
// order 00->01->11->10, loads issued one phase early (vmcnt(0)/phase, only
// 4 VMEM in flight), lgkmcnt(0) before each barrier for write visibility,
// conflict-free XOR-swizzled LDS (R9-verified). Fused bias+maxpool4+rowsum.

typedef float  f32x4   __attribute__((ext_vector_type(4)));
typedef short  bf16x8  __attribute__((ext_vector_type(8)));

__device__ __forceinline__ short f2bf(float f) {
    union { float f; unsigned u; } v; v.f = f;
    unsigned r = v.u + 0x7FFFu + ((v.u >> 16) & 1u);  // round-to-nearest-even
    return (short)(r >> 16);
}

__device__ __forceinline__ bf16x8 cvt8(float4 a, float4 b) {
    bf16x8 r;
    r[0] = f2bf(a.x); r[1] = f2bf(a.y); r[2] = f2bf(a.z); r[3] = f2bf(a.w);
    r[4] = f2bf(b.x); r[5] = f2bf(b.y); r[6] = f2bf(b.z); r[7] = f2bf(b.w);
    return r;
}

// LDS layout per 32KB buffer (R9-verified, 0 bank conflicts): row r, k-slice
// q (16B): short-offset = (r>>3)*512 + (r&7)*64 + (q^(r&7))*8.  Staging is
// linear per chunk (chunk = 8 rows = 1KB); lane l writes chunk bytes
// [l*16,l*16+16) (consecutive lanes -> conflict-free ds_write_b128), and the
// GLOBAL source applies the inverse swizzle: row = c*8+(l>>3), q=(l&7)^(l>>3).
// Frag byte offsets: mm/nn +16 rows = +2048; b-half +32 rows = +4096;
// a-half +64 rows = +8192; buffer stride 32768.

// direct-stage one chunk: 2 f32x4 loads -> cvt -> one ds_write_b128
#define STG(P, DST)                                                            \
    {                                                                          \
        float4 v0 = *(const float4*)(P);                                       \
        float4 v1 = *(const float4*)((P) + 4);                                 \
        *(bf16x8*)(DST) = cvt8(v0, v1);                                        \
    }

__global__ __launch_bounds__(512, 1) void gemm_pool_kernel(
    const float* __restrict__ X, const float* __restrict__ W,
    const float* __restrict__ bias, float* __restrict__ out, int K)
{
    __shared__ short As[32768];   // 2 bufs x (256 rows x 64 k) = 64 KB
    __shared__ short Bs[32768];

    const int tid  = threadIdx.x;
    const int lane = tid & 63;
    const int wid  = tid >> 6;     // 0..7
    const int wr   = wid >> 2;     // 0..1  (wave rows: 128 each)
    const int wc   = wid & 3;      // 0..3  (wave cols: 64 each)
    const int hi   = lane >> 4;    // frag k-slice part
    const int lo   = lane & 15;    // frag row part

    // XCD-aware bijective block swizzle (nwg = 256, divisible by 8).
    const int nwg  = gridDim.x * gridDim.y;
    const int bid  = blockIdx.y * gridDim.x + blockIdx.x;
    const int wgid = (bid & 7) * (nwg >> 3) + (bid >> 3);
    const int brow = (wgid / gridDim.x) * 256;
    const int bcol = (wgid % gridDim.x) * 256;
    const int nk   = K >> 6;       // BK=64 tiles; requires nk even, >= 4

    // ---- thread-constant ds_read bases (R9-verified formulas) ----
    const int slot0 = hi ^ (lo & 7);
    const int slot1 = (4 + hi) ^ (lo & 7);
    const char* baseA0 = (const char*)As + (((wr * 16 + (lo >> 3)) * 512 + (lo & 7) * 64 + slot0 * 8) << 1);
    const char* baseA1 = (const char*)As + (((wr * 16 + (lo >> 3)) * 512 + (lo & 7) * 64 + slot1 * 8) << 1);
    const char* baseB0 = (const char*)Bs + (((wc * 8  + (lo >> 3)) * 512 + (lo & 7) * 64 + slot0 * 8) << 1);
    const char* baseB1 = (const char*)Bs + (((wc * 8  + (lo >> 3)) * 512 + (lo & 7) * 64 + slot1 * 8) << 1);

    // ---- staging chunk ids, LDS write bases, running f32 global pointers ----
    const int idx0 = wid * 2, idx1 = wid * 2 + 1;
    const int cA00 = (idx0 & 7) + ((idx0 >> 3) << 4), cA10 = (idx1 & 7) + ((idx1 >> 3) << 4);
    const int cA01 = cA00 + 8,                         cA11 = cA10 + 8;
    const int cB00 = ((idx0 >> 2) << 3) + (idx0 & 3),  cB10 = ((idx1 >> 2) << 3) + (idx1 & 3);
    const int cB01 = cB00 + 4,                         cB11 = cB10 + 4;
    const int grow = lane >> 3;
    const int gq8  = ((lane & 7) ^ (lane >> 3)) * 8;   // float offset
    short* Awr = As + lane * 8;   // + chunk*512 (+ buf*16384)
    short* Bwr = Bs + lane * 8;

    const float* pA00 = X + (size_t)(brow + cA00 * 8 + grow) * K + gq8;
    const float* pA10 = X + (size_t)(brow + cA10 * 8 + grow) * K + gq8;
    const float* pA01 = X + (size_t)(brow + cA01 * 8 + grow) * K + gq8;
    const float* pA11 = X + (size_t)(brow + cA11 * 8 + grow) * K + gq8;
    const float* pB00 = W + (size_t)(bcol + cB00 * 8 + grow) * K + gq8;
    const float* pB10 = W + (size_t)(bcol + cB10 * 8 + grow) * K + gq8;
    const float* pB01 = W + (size_t)(bcol + cB01 * 8 + grow) * K + gq8;
    const float* pB11 = W + (size_t)(bcol + cB11 * 8 + grow) * K + gq8;

    f32x4 acc[8][4] = {};
    bf16x8 a[4][2], b[2][2];
    float4 L0, L1, L2, L3;         // single in-flight load set (16 VGPR)

    // ---- prologue: tile 0 fully + tile 1 minus its B0; preload L = B0(1) ----
    STG(pA00, Awr + cA00 * 512); STG(pA10, Awr + cA10 * 512);               // A0(0)
    STG(pB00, Bwr + cB00 * 512); STG(pB10, Bwr + cB10 * 512);               // B0(0)
    STG(pB01, Bwr + cB01 * 512); STG(pB11, Bwr + cB11 * 512);               // B1(0)
    STG(pA01, Awr + cA01 * 512); STG(pA11, Awr + cA11 * 512);               // A1(0)
    STG(pA00 + 64, Awr + 16384 + cA00 * 512); STG(pA10 + 64, Awr + 16384 + cA10 * 512); // A0(1)
    STG(pB01 + 64, Bwr + 16384 + cB01 * 512); STG(pB11 + 64, Bwr + 16384 + cB11 * 512); // B1(1)
    STG(pA01 + 64, Awr + 16384 + cA01 * 512); STG(pA11 + 64, Awr + 16384 + cA11 * 512); // A1(1)
    L0 = *(const float4*)(pB00 + 64); L1 = *(const float4*)(pB00 + 68);     // B0(1) in-flight
    L2 = *(const float4*)(pB10 + 64); L3 = *(const float4*)(pB10 + 68);
    pA00 += 128; pA10 += 128; pA01 += 128; pA11 += 128;
    pB00 += 128; pB10 += 128; pB01 += 128; pB11 += 128;   // now at kt = 2
    asm volatile("s_waitcnt lgkmcnt(0)" ::: "memory");
    __builtin_amdgcn_s_barrier();

    // Phase = {barrier; frag ds_reads; vmcnt(0); cvt+ds_write(prev loads);
    //          issue next f32 loads; MFMA; lgkmcnt(0)}.
    // WAR slots identical to R10 (audited); RAW: lgkmcnt(0)-before-barrier
    // publishes ds_writes; reads happen >= 4 barriers later.
#define TILE_BODY(T, BUF)                                                          \
    {                                                                              \
        /* P1: reads a0(8)+b0(4); write B0(T+1)->other buf; load A0(T+2) */        \
        __builtin_amdgcn_s_barrier();                                              \
        _Pragma("unroll")                                                          \
        for (int mm = 0; mm < 4; ++mm) {                                           \
            a[mm][0] = *(const bf16x8*)(baseA0 + (BUF)*32768 + mm*2048);           \
            a[mm][1] = *(const bf16x8*)(baseA1 + (BUF)*32768 + mm*2048);           \
        }                                                                          \
        _Pragma("unroll")                                                          \
        for (int nn = 0; nn < 2; ++nn) {                                           \
            b[nn][0] = *(const bf16x8*)(baseB0 + (BUF)*32768 + nn*2048);           \
            b[nn][1] = *(const bf16x8*)(baseB1 + (BUF)*32768 + nn*2048);           \
        }                                                                          \
        asm volatile("s_waitcnt vmcnt(0)" ::: "memory");                           \
        if ((T) + 1 < nk) {                                                        \
            *(bf16x8*)(Bwr + (1-(BUF))*16384 + cB00*512) = cvt8(L0, L1);           \
            *(bf16x8*)(Bwr + (1-(BUF))*16384 + cB10*512) = cvt8(L2, L3);           \
        }                                                                          \
        L0 = *(const float4*)(pA00); L1 = *(const float4*)(pA00 + 4);              \
        L2 = *(const float4*)(pA10); L3 = *(const float4*)(pA10 + 4);              \
        __builtin_amdgcn_s_setprio(1);                                             \
        _Pragma("unroll")                                                          \
        for (int mm = 0; mm < 4; ++mm)                                             \
            _Pragma("unroll")                                                      \
            for (int nn = 0; nn < 2; ++nn)                                         \
                _Pragma("unroll")                                                  \
                for (int kk = 0; kk < 2; ++kk)                                     \
                    acc[mm][nn] = __builtin_amdgcn_mfma_f32_16x16x32_bf16(         \
                        a[mm][kk], b[nn][kk], acc[mm][nn], 0, 0, 0);               \
        __builtin_amdgcn_s_setprio(0);                                             \
        asm volatile("s_waitcnt lgkmcnt(0)" ::: "memory");                         \
        /* P2: reads b1(4); write A0(T+2)->same buf; load B1(T+2) */               \
        __builtin_amdgcn_s_barrier();                                              \
        _Pragma("unroll")                                                          \
        for (int nn = 0; nn < 2; ++nn) {                                           \
            b[nn][0] = *(const bf16x8*)(baseB0 + (BUF)*32768 + nn*2048 + 4096);    \
            b[nn][1] = *(const bf16x8*)(baseB1 + (BUF)*32768 + nn*2048 + 4096);    \
        }                                                                          \
        asm volatile("s_waitcnt vmcnt(0)" ::: "memory");                           \
        if ((T) + 2 < nk) {                                                        \
            *(bf16x8*)(Awr + (BUF)*16384 + cA00*512) = cvt8(L0, L1);               \
            *(bf16x8*)(Awr + (BUF)*16384 + cA10*512) = cvt8(L2, L3);               \
        }                                                                          \
        L0 = *(const float4*)(pB01); L1 = *(const float4*)(pB01 + 4);              \
        L2 = *(const float4*)(pB11); L3 = *(const float4*)(pB11 + 4);              \
        __builtin_amdgcn_s_setprio(1);                                             \
        _Pragma("unroll")                                                          \
        for (int mm = 0; mm < 4; ++mm)                                             \
            _Pragma("unroll")                                                      \
            for (int nn = 0; nn < 2; ++nn)                                         \
                _Pragma("unroll")                                                  \
                for (int kk = 0; kk < 2; ++kk)                                     \
                    acc[mm][2+nn] = __builtin_amdgcn_mfma_f32_16x16x32_bf16(       \
                        a[mm][kk], b[nn][kk], acc[mm][2+nn], 0, 0, 0);             \
        __builtin_amdgcn_s_setprio(0);                                             \
        asm volatile("s_waitcnt lgkmcnt(0)" ::: "memory");                         \
        /* P3: reads a1(8) [+8192]; write B1(T+2); load A1(T+2) */                 \
        __builtin_amdgcn_s_barrier();                                              \
        _Pragma("unroll")                                                          \
        for (int mm = 0; mm < 4; ++mm) {                                           \
            a[mm][0] = *(const bf16x8*)(baseA0 + (BUF)*32768 + mm*2048 + 8192);    \
            a[mm][1] = *(const bf16x8*)(baseA1 + (BUF)*32768 + mm*2048 + 8192);    \
        }                                                                          \
        asm volatile("s_waitcnt vmcnt(0)" ::: "memory");                           \
        if ((T) + 2 < nk) {                                                        \
            *(bf16x8*)(Bwr + (BUF)*16384 + cB01*512) = cvt8(L0, L1);               \
            *(bf16x8*)(Bwr + (BUF)*16384 + cB11*512) = cvt8(L2, L3);               \
        }                                                                          \
        L0 = *(const float4*)(pA01); L1 = *(const float4*)(pA01 + 4);              \
        L2 = *(const float4*)(pA11); L3 = *(const float4*)(pA11 + 4);              \
        __builtin_amdgcn_s_setprio(1);                                             \
        _Pragma("unroll")                                                          \
        for (int mm = 0; mm < 4; ++mm)                                             \
            _Pragma("unroll")                                                      \
            for (int nn = 0; nn < 2; ++nn)                                         \
                _Pragma("unroll")                                                  \
                for (int kk = 0; kk < 2; ++kk)                                     \
                    acc[4+mm][2+nn] = __builtin_amdgcn_mfma_f32_16x16x32_bf16(     \
                        a[mm][kk], b[nn][kk], acc[4+mm][2+nn], 0, 0, 0);           \
        __builtin_amdgcn_s_setprio(0);                                             \
        asm volatile("s_waitcnt lgkmcnt(0)" ::: "memory");                         \
        /* P4: re-reads b0(4); write A1(T+2); load B0(T+2) */                      \
        __builtin_amdgcn_s_barrier();                                              \
        _Pragma("unroll")                                                          \
        for (int nn = 0; nn < 2; ++nn) {                                           \
            b[nn][0] = *(const bf16x8*)(baseB0 + (BUF)*32768 + nn*2048);           \
            b[nn][1] = *(const bf16x8*)(baseB1 + (BUF)*32768 + nn*2048);           \
        }                                                                          \
        asm volatile("s_waitcnt vmcnt(0)" ::: "memory");                           \
        if ((T) + 2 < nk) {                                                        \
            *(bf16x8*)(Awr + (BUF)*16384 + cA01*512) = cvt8(L0, L1);               \
            *(bf16x8*)(Awr + (BUF)*16384 + cA11*512) = cvt8(L2, L3);               \
        }                                                                          \
        L0 = *(const float4*)(pB00); L1 = *(const float4*)(pB00 + 4);              \
        L2 = *(const float4*)(pB10); L3 = *(const float4*)(pB10 + 4);              \
        __builtin_amdgcn_s_setprio(1);                                             \
        _Pragma("unroll")                                                          \
        for (int mm = 0; mm < 4; ++mm)                                             \
            _Pragma("unroll")                                                      \
            for (int nn = 0; nn < 2; ++nn)                                         \
                _Pragma("unroll")                                                  \
                for (int kk = 0; kk < 2; ++kk)                                     \
                    acc[4+mm][nn] = __builtin_amdgcn_mfma_f32_16x16x32_bf16(       \
                        a[mm][kk], b[nn][kk], acc[4+mm][nn], 0, 0, 0);             \
        __builtin_amdgcn_s_setprio(0);                                             \
        asm volatile("s_waitcnt lgkmcnt(0)" ::: "memory");                         \
        if ((T) + 3 < nk) {                                                        \
            pA00 += 64; pA10 += 64; pA01 += 64; pA11 += 64;                        \
            pB00 += 64; pB10 += 64; pB01 += 64; pB11 += 64;                        \
        }                                                                          \
    }

    for (int t = 0; t < nk; t += 2) {
        TILE_BODY(t, 0);
        TILE_BODY(t + 1, 1);
    }
#undef TILE_BODY

    // Epilogue: bias + maxpool4(cols) + rowsum, fused.
    // C/D frag mapping: col = lane&15, row = (lane>>4)*4 + reg  [m89-verified]
    float bias_n[4];
#pragma unroll
    for (int nn = 0; nn < 4; ++nn)
        bias_n[nn] = bias[bcol + wc * 64 + nn * 16 + lo];

#pragma unroll
    for (int mm = 0; mm < 8; ++mm) {
#pragma unroll
        for (int j = 0; j < 4; ++j) {
            float part = 0.f;
#pragma unroll
            for (int nn = 0; nn < 4; ++nn) {
                float v = acc[mm][nn][j] + bias_n[nn];
                v = fmaxf(v, __shfl_xor(v, 1));   // pool across col bit 0
                v = fmaxf(v, __shfl_xor(v, 2));   // pool across col bit 1
                part += v;                        // lane holds pooled[(lo>>2)]
            }
            part += __shfl_xor(part, 4);          // sum the 4 pool groups
            part += __shfl_xor(part, 8);
            if (lo == 0)
                atomicAdd(&out[brow + wr * 128 + mm * 16 + hi * 4 + j], part * 0.5f);
        }
    }
}

extern "C" void kernel_launch(void* const* d_in, const int* in_sizes, int n_in,
                              void* d_out, int out_size, void* d_ws, size_t ws_size,
                              hipStream_t stream) {
    const float* x = (const float*)d_in[0];
    const float* W = (const float*)d_in[1];
    const float* b = (const float*)d_in[2];
    float* out = (float*)d_out;

    const int N = in_sizes[2];             // out_f = 4096
    const int K = in_sizes[1] / N;         // in_f  = 2048
    const int M = in_sizes[0] / K;         // batch = 4096

    // Atomics accumulate into out -> must zero every call (graph replays).
    hipMemsetAsync(out, 0, (size_t)out_size * sizeof(float), stream);

    dim3 grid(N / 256, M / 256);           // 256 blocks
    gemm_pool_kernel<<<grid, 512, 0, stream>>>(x, W, b, out, K);
}

// Round 13
// 85.782 us; speedup vs baseline: 1.6333x; 1.6333x over previous
//
#include <hip/hip_runtime.h>

// out = 0.5 * sum_over_pooled( maxpool4( x @ W^T + b ) )  -> (batch,) fp32
// x: (M=4096, K=2048) f32, W: (N=4096, K=2048) f32, b: (N,) f32, out: (M,) f32
// Strategy (best-measured config, R10): cvt to bf16 in ws (also zeroes out,
// replacing the memset dispatch); 256x256 BK=64 8-wave MFMA GEMM.
// Schedule: ONE barrier per phase ({barrier; ds_reads; stage; lgkm0; MFMA}),
// quadrant order 00->01->11->10 with register-held b0/b1 (24 reads/tile),
// counted vmcnt(6) per tile, setprio, conflict-free XOR-swizzled LDS,
// launch_bounds(512,1). Fused bias+maxpool4+rowsum epilogue with atomicAdd.

typedef float  f32x4   __attribute__((ext_vector_type(4)));
typedef short  bf16x8  __attribute__((ext_vector_type(8)));
typedef short  short4v __attribute__((ext_vector_type(4)));

__device__ __forceinline__ short f2bf(float f) {
    union { float f; unsigned u; } v; v.f = f;
    unsigned r = v.u + 0x7FFFu + ((v.u >> 16) & 1u);  // round-to-nearest-even
    return (short)(r >> 16);
}

__global__ void cvt_kernel(const float* __restrict__ x, const float* __restrict__ w,
                           short* __restrict__ out, long nx, long nw,
                           float* __restrict__ zout, int zn) {
    long stride = (long)gridDim.x * blockDim.x;
    long tid0   = (long)blockIdx.x * blockDim.x + threadIdx.x;
    // zero the output vector (replaces a separate memset dispatch; atomics
    // accumulate into it every graph replay)
    for (long i = tid0; i < zn; i += stride) zout[i] = 0.f;
    long total4 = (nx + nw) >> 2;
    for (long i = tid0; i < total4; i += stride) {
        long e = i << 2;
        const float* src = (e < nx) ? (x + e) : (w + (e - nx));
        float4 v = *(const float4*)src;
        short4v s = { f2bf(v.x), f2bf(v.y), f2bf(v.z), f2bf(v.w) };
        *(short4v*)(out + e) = s;
    }
}

// LDS layout per 32KB buffer: row r (0..255), k-slice q (0..7 16B slices):
// short-offset = (r>>3)*512 + (r&7)*64 + (q^(r&7))*8.  Conflict-free
// ds_read_b128 (verified: SQ_LDS_BANK_CONFLICT=0). Staging linear per chunk
// (8 rows = 1KB = one wave-wide global_load_lds); global source applies the
// inverse swizzle: row = c*8 + (l>>3), q = (l&7)^(l>>3).
// Byte offsets: mm/nn +16 rows = +2048 B; b-half +32 rows = +4096 B;
// a-half +64 rows = +8192 B; buffer stride 32768 B.

#define GLL(gp, ldsp)                                                          \
    __builtin_amdgcn_global_load_lds(                                          \
        (const __attribute__((address_space(1))) unsigned int*)(gp),           \
        (__attribute__((address_space(3))) unsigned int*)(ldsp), 16, 0, 0)

__global__ __launch_bounds__(512, 1) void gemm_pool_kernel(
    const short* __restrict__ X, const short* __restrict__ W,
    const float* __restrict__ bias, float* __restrict__ out, int K)
{
    __shared__ short As[32768];   // 2 bufs x (256 rows x 64 k) = 64 KB
    __shared__ short Bs[32768];   // 64 KB

    const int tid  = threadIdx.x;
    const int lane = tid & 63;
    const int wid  = tid >> 6;     // 0..7
    const int wr   = wid >> 2;     // 0..1  (wave rows: 128 each)
    const int wc   = wid & 3;      // 0..3  (wave cols: 64 each)
    const int hi   = lane >> 4;    // frag k-slice part
    const int lo   = lane & 15;    // frag row part

    // XCD-aware bijective block swizzle (nwg = 256, divisible by 8).
    const int nwg  = gridDim.x * gridDim.y;
    const int bid  = blockIdx.y * gridDim.x + blockIdx.x;
    const int wgid = (bid & 7) * (nwg >> 3) + (bid >> 3);
    const int brow = (wgid / gridDim.x) * 256;
    const int bcol = (wgid % gridDim.x) * 256;
    const int nk   = K >> 6;       // BK=64 tiles; requires nk even, >= 4

    // ---- thread-constant ds_read bases (all loop reads = base + imm) ----
    const int slot0 = hi ^ (lo & 7);
    const int slot1 = (4 + hi) ^ (lo & 7);
    const char* baseA0 = (const char*)As + (((wr * 16 + (lo >> 3)) * 512 + (lo & 7) * 64 + slot0 * 8) << 1);
    const char* baseA1 = (const char*)As + (((wr * 16 + (lo >> 3)) * 512 + (lo & 7) * 64 + slot1 * 8) << 1);
    const char* baseB0 = (const char*)Bs + (((wc * 8  + (lo >> 3)) * 512 + (lo & 7) * 64 + slot0 * 8) << 1);
    const char* baseB1 = (const char*)Bs + (((wc * 8  + (lo >> 3)) * 512 + (lo & 7) * 64 + slot1 * 8) << 1);

    // ---- staging chunk ids and running global pointers (kt = 0) ----
    const int idx0 = wid * 2, idx1 = wid * 2 + 1;
    const int cA00 = (idx0 & 7) + ((idx0 >> 3) << 4), cA10 = (idx1 & 7) + ((idx1 >> 3) << 4);
    const int cA01 = cA00 + 8,                         cA11 = cA10 + 8;
    const int cB00 = ((idx0 >> 2) << 3) + (idx0 & 3),  cB10 = ((idx1 >> 2) << 3) + (idx1 & 3);
    const int cB01 = cB00 + 4,                         cB11 = cB10 + 4;
    const int grow = lane >> 3;
    const int gq8  = ((lane & 7) ^ (lane >> 3)) * 8;

    const short* pA00 = X + (size_t)(brow + cA00 * 8 + grow) * K + gq8;
    const short* pA10 = X + (size_t)(brow + cA10 * 8 + grow) * K + gq8;
    const short* pA01 = X + (size_t)(brow + cA01 * 8 + grow) * K + gq8;
    const short* pA11 = X + (size_t)(brow + cA11 * 8 + grow) * K + gq8;
    const short* pB00 = W + (size_t)(bcol + cB00 * 8 + grow) * K + gq8;
    const short* pB10 = W + (size_t)(bcol + cB10 * 8 + grow) * K + gq8;
    const short* pB01 = W + (size_t)(bcol + cB01 * 8 + grow) * K + gq8;
    const short* pB11 = W + (size_t)(bcol + cB11 * 8 + grow) * K + gq8;

    f32x4 acc[8][4] = {};
    bf16x8 a[4][2], b0[2][2], b1[2][2];

    // ---- prologue: tile 0 fully + {A0,B1,A1}(1) ----
    GLL(pA00, As + cA00 * 512); GLL(pA10, As + cA10 * 512);               // A0(0)
    GLL(pB00, Bs + cB00 * 512); GLL(pB10, Bs + cB10 * 512);               // B0(0)
    GLL(pB01, Bs + cB01 * 512); GLL(pB11, Bs + cB11 * 512);               // B1(0)
    GLL(pA01, As + cA01 * 512); GLL(pA11, As + cA11 * 512);               // A1(0)
    GLL(pA00 + 64, As + 16384 + cA00 * 512); GLL(pA10 + 64, As + 16384 + cA10 * 512); // A0(1)
    GLL(pB01 + 64, Bs + 16384 + cB01 * 512); GLL(pB11 + 64, Bs + 16384 + cB11 * 512); // B1(1)
    GLL(pA01 + 64, As + 16384 + cA01 * 512); GLL(pA11 + 64, As + 16384 + cA11 * 512); // A1(1)
    pA00 += 128; pA10 += 128; pA01 += 128; pA11 += 128;
    pB00 += 128; pB10 += 128; pB01 += 128; pB11 += 128;   // now at kt = 2
    asm volatile("s_waitcnt vmcnt(6)" ::: "memory");       // tile-0 complete

    // Phase = {barrier; ds_reads; stage; lgkm0; setprio; MFMA}. No post-MFMA
    // barrier: the next phase's barrier provides the WAR fence (each wave's
    // reads are lgkm0-drained before it arrives). Quadrants 00,01,11,10 with
    // b0 held P1->P4 and b1 held P2->P3 (P4 reads nothing).
#define TILE_BODY(T, BUF)                                                          \
    {                                                                              \
        /* P1: reads a0(8)+b0(4); stage B0(T+1)->other buf; MFMA (0,0) */          \
        __builtin_amdgcn_s_barrier();                                              \
        _Pragma("unroll")                                                          \
        for (int mm = 0; mm < 4; ++mm) {                                           \
            a[mm][0] = *(const bf16x8*)(baseA0 + (BUF)*32768 + mm*2048);           \
            a[mm][1] = *(const bf16x8*)(baseA1 + (BUF)*32768 + mm*2048);           \
        }                                                                          \
        _Pragma("unroll")                                                          \
        for (int nn = 0; nn < 2; ++nn) {                                           \
            b0[nn][0] = *(const bf16x8*)(baseB0 + (BUF)*32768 + nn*2048);          \
            b0[nn][1] = *(const bf16x8*)(baseB1 + (BUF)*32768 + nn*2048);          \
        }                                                                          \
        if ((T) + 1 < nk) {                                                        \
            GLL(pB00 - 64, Bs + (1-(BUF))*16384 + cB00*512);                       \
            GLL(pB10 - 64, Bs + (1-(BUF))*16384 + cB10*512);                       \
        }                                                                          \
        asm volatile("s_waitcnt lgkmcnt(0)" ::: "memory");                         \
        __builtin_amdgcn_s_setprio(1);                                             \
        _Pragma("unroll")                                                          \
        for (int mm = 0; mm < 4; ++mm)                                             \
            _Pragma("unroll")                                                      \
            for (int nn = 0; nn < 2; ++nn)                                         \
                _Pragma("unroll")                                                  \
                for (int kk = 0; kk < 2; ++kk)                                     \
                    acc[mm][nn] = __builtin_amdgcn_mfma_f32_16x16x32_bf16(         \
                        a[mm][kk], b0[nn][kk], acc[mm][nn], 0, 0, 0);              \
        __builtin_amdgcn_s_setprio(0);                                             \
        /* P2: reads b1(4); stage A0(T+2)->same buf; MFMA (0,1) */                 \
        __builtin_amdgcn_s_barrier();                                              \
        _Pragma("unroll")                                                          \
        for (int nn = 0; nn < 2; ++nn) {                                           \
            b1[nn][0] = *(const bf16x8*)(baseB0 + (BUF)*32768 + nn*2048 + 4096);   \
            b1[nn][1] = *(const bf16x8*)(baseB1 + (BUF)*32768 + nn*2048 + 4096);   \
        }                                                                          \
        if ((T) + 2 < nk) {                                                        \
            GLL(pA00, As + (BUF)*16384 + cA00*512);                                \
            GLL(pA10, As + (BUF)*16384 + cA10*512);                                \
        }                                                                          \
        asm volatile("s_waitcnt lgkmcnt(0)" ::: "memory");                         \
        __builtin_amdgcn_s_setprio(1);                                             \
        _Pragma("unroll")                                                          \
        for (int mm = 0; mm < 4; ++mm)                                             \
            _Pragma("unroll")                                                      \
            for (int nn = 0; nn < 2; ++nn)                                         \
                _Pragma("unroll")                                                  \
                for (int kk = 0; kk < 2; ++kk)                                     \
                    acc[mm][2+nn] = __builtin_amdgcn_mfma_f32_16x16x32_bf16(       \
                        a[mm][kk], b1[nn][kk], acc[mm][2+nn], 0, 0, 0);            \
        __builtin_amdgcn_s_setprio(0);                                             \
        /* P3: reads a1(8) [+8192B]; stage B1(T+2); MFMA (1,1) [b1 held] */        \
        __builtin_amdgcn_s_barrier();                                              \
        _Pragma("unroll")                                                          \
        for (int mm = 0; mm < 4; ++mm) {                                           \
            a[mm][0] = *(const bf16x8*)(baseA0 + (BUF)*32768 + mm*2048 + 8192);    \
            a[mm][1] = *(const bf16x8*)(baseA1 + (BUF)*32768 + mm*2048 + 8192);    \
        }                                                                          \
        if ((T) + 2 < nk) {                                                        \
            GLL(pB01, Bs + (BUF)*16384 + cB01*512);                                \
            GLL(pB11, Bs + (BUF)*16384 + cB11*512);                                \
        }                                                                          \
        asm volatile("s_waitcnt lgkmcnt(0)" ::: "memory");                         \
        __builtin_amdgcn_s_setprio(1);                                             \
        _Pragma("unroll")                                                          \
        for (int mm = 0; mm < 4; ++mm)                                             \
            _Pragma("unroll")                                                      \
            for (int nn = 0; nn < 2; ++nn)                                         \
                _Pragma("unroll")                                                  \
                for (int kk = 0; kk < 2; ++kk)                                     \
                    acc[4+mm][2+nn] = __builtin_amdgcn_mfma_f32_16x16x32_bf16(     \
                        a[mm][kk], b1[nn][kk], acc[4+mm][2+nn], 0, 0, 0);          \
        __builtin_amdgcn_s_setprio(0);                                             \
        /* P4: no reads; stage A1(T+2); MFMA (1,0) [b0 held]; boundary */          \
        __builtin_amdgcn_s_barrier();                                              \
        if ((T) + 2 < nk) {                                                        \
            GLL(pA01, As + (BUF)*16384 + cA01*512);                                \
            GLL(pA11, As + (BUF)*16384 + cA11*512);                                \
        }                                                                          \
        __builtin_amdgcn_s_setprio(1);                                             \
        _Pragma("unroll")                                                          \
        for (int mm = 0; mm < 4; ++mm)                                             \
            _Pragma("unroll")                                                      \
            for (int nn = 0; nn < 2; ++nn)                                         \
                _Pragma("unroll")                                                  \
                for (int kk = 0; kk < 2; ++kk)                                     \
                    acc[4+mm][nn] = __builtin_amdgcn_mfma_f32_16x16x32_bf16(       \
                        a[mm][kk], b0[nn][kk], acc[4+mm][nn], 0, 0, 0);            \
        __builtin_amdgcn_s_setprio(0);                                             \
        if ((T) == nk - 2)      asm volatile("s_waitcnt vmcnt(0)" ::: "memory");   \
        else if ((T) < nk - 2)  asm volatile("s_waitcnt vmcnt(6)" ::: "memory");   \
        pA00 += 64; pA10 += 64; pA01 += 64; pA11 += 64;                            \
        pB00 += 64; pB10 += 64; pB01 += 64; pB11 += 64;                            \
    }

    for (int t = 0; t < nk; t += 2) {
        TILE_BODY(t, 0);
        TILE_BODY(t + 1, 1);
    }
#undef TILE_BODY

    // Epilogue: bias + maxpool4(cols) + rowsum, fused.
    // C/D frag mapping: col = lane&15, row = (lane>>4)*4 + reg  [m89-verified]
    float bias_n[4];
#pragma unroll
    for (int nn = 0; nn < 4; ++nn)
        bias_n[nn] = bias[bcol + wc * 64 + nn * 16 + lo];

#pragma unroll
    for (int mm = 0; mm < 8; ++mm) {
#pragma unroll
        for (int j = 0; j < 4; ++j) {
            float part = 0.f;
#pragma unroll
            for (int nn = 0; nn < 4; ++nn) {
                float v = acc[mm][nn][j] + bias_n[nn];
                v = fmaxf(v, __shfl_xor(v, 1));   // pool across col bit 0
                v = fmaxf(v, __shfl_xor(v, 2));   // pool across col bit 1
                part += v;                        // lane holds pooled[(lo>>2)]
            }
            part += __shfl_xor(part, 4);          // sum the 4 pool groups
            part += __shfl_xor(part, 8);
            if (lo == 0)
                atomicAdd(&out[brow + wr * 128 + mm * 16 + hi * 4 + j], part * 0.5f);
        }
    }
}

extern "C" void kernel_launch(void* const* d_in, const int* in_sizes, int n_in,
                              void* d_out, int out_size, void* d_ws, size_t ws_size,
                              hipStream_t stream) {
    const float* x = (const float*)d_in[0];
    const float* W = (const float*)d_in[1];
    const float* b = (const float*)d_in[2];
    float* out = (float*)d_out;

    const int N = in_sizes[2];             // out_f = 4096
    const int K = in_sizes[1] / N;         // in_f  = 2048
    const int M = in_sizes[0] / K;         // batch = 4096

    short* xb = (short*)d_ws;
    short* wb = xb + in_sizes[0];
    // cvt also zeroes `out` (atomics accumulate across graph replays).
    cvt_kernel<<<2048, 256, 0, stream>>>(x, W, (short*)d_ws,
                                         (long)in_sizes[0], (long)in_sizes[1],
                                         out, out_size);

    dim3 grid(N / 256, M / 256);           // 256 blocks
    gemm_pool_kernel<<<grid, 512, 0, stream>>>(xb, wb, b, out, K);
}

// Round 14
// 84.627 us; speedup vs baseline: 1.6556x; 1.0136x over previous
//
#include <hip/hip_runtime.h>

// out = 0.5 * sum_over_pooled( maxpool4( x @ W^T + b ) )  -> (batch,) fp32
// x: (M=4096, K=2048) f32, W: (N=4096, K=2048) f32, b: (N,) f32, out: (M,) f32
// Strategy (R13 + counted-lgkm fix): cvt to bf16 in ws (also zeroes out);
// 256x256 BK=64 8-wave MFMA GEMM. Phase = {barrier; ds_reads (b first);
// stage; setprio; MFMA} with NO hand-written lgkmcnt(0) — the compiler's
// counted lgkm waits let the first MFMA start after its own operands while
// the tail reads complete under the MFMA cluster. WAR: reads are consumed
// by same-phase MFMAs (retired before the next barrier); cross-tile motion
// fenced by the boundary vmcnt asm ("memory"). Counted vmcnt(6) per tile,
// conflict-free XOR-swizzled LDS. Fused bias+maxpool4+rowsum epilogue.

typedef float  f32x4   __attribute__((ext_vector_type(4)));
typedef short  bf16x8  __attribute__((ext_vector_type(8)));
typedef short  short4v __attribute__((ext_vector_type(4)));

__device__ __forceinline__ short f2bf(float f) {
    union { float f; unsigned u; } v; v.f = f;
    unsigned r = v.u + 0x7FFFu + ((v.u >> 16) & 1u);  // round-to-nearest-even
    return (short)(r >> 16);
}

__global__ void cvt_kernel(const float* __restrict__ x, const float* __restrict__ w,
                           short* __restrict__ out, long nx, long nw,
                           float* __restrict__ zout, int zn) {
    long stride = (long)gridDim.x * blockDim.x;
    long tid0   = (long)blockIdx.x * blockDim.x + threadIdx.x;
    // zero the output vector (atomics accumulate into it every graph replay)
    for (long i = tid0; i < zn; i += stride) zout[i] = 0.f;
    long total4 = (nx + nw) >> 2;
    for (long i = tid0; i < total4; i += stride) {
        long e = i << 2;
        const float* src = (e < nx) ? (x + e) : (w + (e - nx));
        float4 v = *(const float4*)src;
        short4v s = { f2bf(v.x), f2bf(v.y), f2bf(v.z), f2bf(v.w) };
        *(short4v*)(out + e) = s;
    }
}

// LDS layout per 32KB buffer: row r (0..255), k-slice q (0..7 16B slices):
// short-offset = (r>>3)*512 + (r&7)*64 + (q^(r&7))*8.  Conflict-free
// ds_read_b128 (verified: SQ_LDS_BANK_CONFLICT=0). Staging linear per chunk
// (8 rows = 1KB = one wave-wide global_load_lds); global source applies the
// inverse swizzle: row = c*8 + (l>>3), q = (l&7)^(l>>3).
// Byte offsets: mm/nn +16 rows = +2048 B; b-half +32 rows = +4096 B;
// a-half +64 rows = +8192 B; buffer stride 32768 B.

#define GLL(gp, ldsp)                                                          \
    __builtin_amdgcn_global_load_lds(                                          \
        (const __attribute__((address_space(1))) unsigned int*)(gp),           \
        (__attribute__((address_space(3))) unsigned int*)(ldsp), 16, 0, 0)

__global__ __launch_bounds__(512, 1) void gemm_pool_kernel(
    const short* __restrict__ X, const short* __restrict__ W,
    const float* __restrict__ bias, float* __restrict__ out, int K)
{
    __shared__ short As[32768];   // 2 bufs x (256 rows x 64 k) = 64 KB
    __shared__ short Bs[32768];   // 64 KB

    const int tid  = threadIdx.x;
    const int lane = tid & 63;
    const int wid  = tid >> 6;     // 0..7
    const int wr   = wid >> 2;     // 0..1  (wave rows: 128 each)
    const int wc   = wid & 3;      // 0..3  (wave cols: 64 each)
    const int hi   = lane >> 4;    // frag k-slice part
    const int lo   = lane & 15;    // frag row part

    // XCD-aware bijective block swizzle (nwg = 256, divisible by 8).
    const int nwg  = gridDim.x * gridDim.y;
    const int bid  = blockIdx.y * gridDim.x + blockIdx.x;
    const int wgid = (bid & 7) * (nwg >> 3) + (bid >> 3);
    const int brow = (wgid / gridDim.x) * 256;
    const int bcol = (wgid % gridDim.x) * 256;
    const int nk   = K >> 6;       // BK=64 tiles; requires nk even, >= 4

    // ---- thread-constant ds_read bases (all loop reads = base + imm) ----
    const int slot0 = hi ^ (lo & 7);
    const int slot1 = (4 + hi) ^ (lo & 7);
    const char* baseA0 = (const char*)As + (((wr * 16 + (lo >> 3)) * 512 + (lo & 7) * 64 + slot0 * 8) << 1);
    const char* baseA1 = (const char*)As + (((wr * 16 + (lo >> 3)) * 512 + (lo & 7) * 64 + slot1 * 8) << 1);
    const char* baseB0 = (const char*)Bs + (((wc * 8  + (lo >> 3)) * 512 + (lo & 7) * 64 + slot0 * 8) << 1);
    const char* baseB1 = (const char*)Bs + (((wc * 8  + (lo >> 3)) * 512 + (lo & 7) * 64 + slot1 * 8) << 1);

    // ---- staging chunk ids and running global pointers (kt = 0) ----
    const int idx0 = wid * 2, idx1 = wid * 2 + 1;
    const int cA00 = (idx0 & 7) + ((idx0 >> 3) << 4), cA10 = (idx1 & 7) + ((idx1 >> 3) << 4);
    const int cA01 = cA00 + 8,                         cA11 = cA10 + 8;
    const int cB00 = ((idx0 >> 2) << 3) + (idx0 & 3),  cB10 = ((idx1 >> 2) << 3) + (idx1 & 3);
    const int cB01 = cB00 + 4,                         cB11 = cB10 + 4;
    const int grow = lane >> 3;
    const int gq8  = ((lane & 7) ^ (lane >> 3)) * 8;

    const short* pA00 = X + (size_t)(brow + cA00 * 8 + grow) * K + gq8;
    const short* pA10 = X + (size_t)(brow + cA10 * 8 + grow) * K + gq8;
    const short* pA01 = X + (size_t)(brow + cA01 * 8 + grow) * K + gq8;
    const short* pA11 = X + (size_t)(brow + cA11 * 8 + grow) * K + gq8;
    const short* pB00 = W + (size_t)(bcol + cB00 * 8 + grow) * K + gq8;
    const short* pB10 = W + (size_t)(bcol + cB10 * 8 + grow) * K + gq8;
    const short* pB01 = W + (size_t)(bcol + cB01 * 8 + grow) * K + gq8;
    const short* pB11 = W + (size_t)(bcol + cB11 * 8 + grow) * K + gq8;

    f32x4 acc[8][4] = {};
    bf16x8 a[4][2], b0[2][2], b1[2][2];

    // ---- prologue: tile 0 fully + {A0,B1,A1}(1) ----
    GLL(pA00, As + cA00 * 512); GLL(pA10, As + cA10 * 512);               // A0(0)
    GLL(pB00, Bs + cB00 * 512); GLL(pB10, Bs + cB10 * 512);               // B0(0)
    GLL(pB01, Bs + cB01 * 512); GLL(pB11, Bs + cB11 * 512);               // B1(0)
    GLL(pA01, As + cA01 * 512); GLL(pA11, As + cA11 * 512);               // A1(0)
    GLL(pA00 + 64, As + 16384 + cA00 * 512); GLL(pA10 + 64, As + 16384 + cA10 * 512); // A0(1)
    GLL(pB01 + 64, Bs + 16384 + cB01 * 512); GLL(pB11 + 64, Bs + 16384 + cB11 * 512); // B1(1)
    GLL(pA01 + 64, As + 16384 + cA01 * 512); GLL(pA11 + 64, As + 16384 + cA11 * 512); // A1(1)
    pA00 += 128; pA10 += 128; pA01 += 128; pA11 += 128;
    pB00 += 128; pB10 += 128; pB01 += 128; pB11 += 128;   // now at kt = 2
    asm volatile("s_waitcnt vmcnt(6)" ::: "memory");       // tile-0 complete

    // Phase = {barrier; ds_reads (b first); stage; setprio; MFMA}.
    // No explicit lgkm drain: MFMA data deps give counted lgkm waits; all
    // reads are consumed before the next barrier (WAR-safe). Quadrants
    // 00,01,11,10 with b0 held P1->P4 and b1 held P2->P3 (P4 reads nothing).
#define TILE_BODY(T, BUF)                                                          \
    {                                                                              \
        /* P1: reads b0(4)+a0(8); stage B0(T+1)->other buf; MFMA (0,0) */          \
        __builtin_amdgcn_s_barrier();                                              \
        _Pragma("unroll")                                                          \
        for (int nn = 0; nn < 2; ++nn) {                                           \
            b0[nn][0] = *(const bf16x8*)(baseB0 + (BUF)*32768 + nn*2048);          \
            b0[nn][1] = *(const bf16x8*)(baseB1 + (BUF)*32768 + nn*2048);          \
        }                                                                          \
        _Pragma("unroll")                                                          \
        for (int mm = 0; mm < 4; ++mm) {                                           \
            a[mm][0] = *(const bf16x8*)(baseA0 + (BUF)*32768 + mm*2048);           \
            a[mm][1] = *(const bf16x8*)(baseA1 + (BUF)*32768 + mm*2048);           \
        }                                                                          \
        if ((T) + 1 < nk) {                                                        \
            GLL(pB00 - 64, Bs + (1-(BUF))*16384 + cB00*512);                       \
            GLL(pB10 - 64, Bs + (1-(BUF))*16384 + cB10*512);                       \
        }                                                                          \
        __builtin_amdgcn_s_setprio(1);                                             \
        _Pragma("unroll")                                                          \
        for (int mm = 0; mm < 4; ++mm)                                             \
            _Pragma("unroll")                                                      \
            for (int nn = 0; nn < 2; ++nn)                                         \
                _Pragma("unroll")                                                  \
                for (int kk = 0; kk < 2; ++kk)                                     \
                    acc[mm][nn] = __builtin_amdgcn_mfma_f32_16x16x32_bf16(         \
                        a[mm][kk], b0[nn][kk], acc[mm][nn], 0, 0, 0);              \
        __builtin_amdgcn_s_setprio(0);                                             \
        /* P2: reads b1(4); stage A0(T+2)->same buf; MFMA (0,1) */                 \
        __builtin_amdgcn_s_barrier();                                              \
        _Pragma("unroll")                                                          \
        for (int nn = 0; nn < 2; ++nn) {                                           \
            b1[nn][0] = *(const bf16x8*)(baseB0 + (BUF)*32768 + nn*2048 + 4096);   \
            b1[nn][1] = *(const bf16x8*)(baseB1 + (BUF)*32768 + nn*2048 + 4096);   \
        }                                                                          \
        if ((T) + 2 < nk) {                                                        \
            GLL(pA00, As + (BUF)*16384 + cA00*512);                                \
            GLL(pA10, As + (BUF)*16384 + cA10*512);                                \
        }                                                                          \
        __builtin_amdgcn_s_setprio(1);                                             \
        _Pragma("unroll")                                                          \
        for (int mm = 0; mm < 4; ++mm)                                             \
            _Pragma("unroll")                                                      \
            for (int nn = 0; nn < 2; ++nn)                                         \
                _Pragma("unroll")                                                  \
                for (int kk = 0; kk < 2; ++kk)                                     \
                    acc[mm][2+nn] = __builtin_amdgcn_mfma_f32_16x16x32_bf16(       \
                        a[mm][kk], b1[nn][kk], acc[mm][2+nn], 0, 0, 0);            \
        __builtin_amdgcn_s_setprio(0);                                             \
        /* P3: reads a1(8) [+8192B]; stage B1(T+2); MFMA (1,1) [b1 held] */        \
        __builtin_amdgcn_s_barrier();                                              \
        _Pragma("unroll")                                                          \
        for (int mm = 0; mm < 4; ++mm) {                                           \
            a[mm][0] = *(const bf16x8*)(baseA0 + (BUF)*32768 + mm*2048 + 8192);    \
            a[mm][1] = *(const bf16x8*)(baseA1 + (BUF)*32768 + mm*2048 + 8192);    \
        }                                                                          \
        if ((T) + 2 < nk) {                                                        \
            GLL(pB01, Bs + (BUF)*16384 + cB01*512);                                \
            GLL(pB11, Bs + (BUF)*16384 + cB11*512);                                \
        }                                                                          \
        __builtin_amdgcn_s_setprio(1);                                             \
        _Pragma("unroll")                                                          \
        for (int mm = 0; mm < 4; ++mm)                                             \
            _Pragma("unroll")                                                      \
            for (int nn = 0; nn < 2; ++nn)                                         \
                _Pragma("unroll")                                                  \
                for (int kk = 0; kk < 2; ++kk)                                     \
                    acc[4+mm][2+nn] = __builtin_amdgcn_mfma_f32_16x16x32_bf16(     \
                        a[mm][kk], b1[nn][kk], acc[4+mm][2+nn], 0, 0, 0);          \
        __builtin_amdgcn_s_setprio(0);                                             \
        /* P4: no reads; stage A1(T+2); MFMA (1,0) [b0 held]; boundary */          \
        __builtin_amdgcn_s_barrier();                                              \
        if ((T) + 2 < nk) {                                                        \
            GLL(pA01, As + (BUF)*16384 + cA01*512);                                \
            GLL(pA11, As + (BUF)*16384 + cA11*512);                                \
        }                                                                          \
        __builtin_amdgcn_s_setprio(1);                                             \
        _Pragma("unroll")                                                          \
        for (int mm = 0; mm < 4; ++mm)                                             \
            _Pragma("unroll")                                                      \
            for (int nn = 0; nn < 2; ++nn)                                         \
                _Pragma("unroll")                                                  \
                for (int kk = 0; kk < 2; ++kk)                                     \
                    acc[4+mm][nn] = __builtin_amdgcn_mfma_f32_16x16x32_bf16(       \
                        a[mm][kk], b0[nn][kk], acc[4+mm][nn], 0, 0, 0);            \
        __builtin_amdgcn_s_setprio(0);                                             \
        if ((T) == nk - 2)      asm volatile("s_waitcnt vmcnt(0)" ::: "memory");   \
        else if ((T) < nk - 2)  asm volatile("s_waitcnt vmcnt(6)" ::: "memory");   \
        pA00 += 64; pA10 += 64; pA01 += 64; pA11 += 64;                            \
        pB00 += 64; pB10 += 64; pB01 += 64; pB11 += 64;                            \
    }

    for (int t = 0; t < nk; t += 2) {
        TILE_BODY(t, 0);
        TILE_BODY(t + 1, 1);
    }
#undef TILE_BODY

    // Epilogue: bias + maxpool4(cols) + rowsum, fused.
    // C/D frag mapping: col = lane&15, row = (lane>>4)*4 + reg  [m89-verified]
    float bias_n[4];
#pragma unroll
    for (int nn = 0; nn < 4; ++nn)
        bias_n[nn] = bias[bcol + wc * 64 + nn * 16 + lo];

#pragma unroll
    for (int mm = 0; mm < 8; ++mm) {
#pragma unroll
        for (int j = 0; j < 4; ++j) {
            float part = 0.f;
#pragma unroll
            for (int nn = 0; nn < 4; ++nn) {
                float v = acc[mm][nn][j] + bias_n[nn];
                v = fmaxf(v, __shfl_xor(v, 1));   // pool across col bit 0
                v = fmaxf(v, __shfl_xor(v, 2));   // pool across col bit 1
                part += v;                        // lane holds pooled[(lo>>2)]
            }
            part += __shfl_xor(part, 4);          // sum the 4 pool groups
            part += __shfl_xor(part, 8);
            if (lo == 0)
                atomicAdd(&out[brow + wr * 128 + mm * 16 + hi * 4 + j], part * 0.5f);
        }
    }
}

extern "C" void kernel_launch(void* const* d_in, const int* in_sizes, int n_in,
                              void* d_out, int out_size, void* d_ws, size_t ws_size,
                              hipStream_t stream) {
    const float* x = (const float*)d_in[0];
    const float* W = (const float*)d_in[1];
    const float* b = (const float*)d_in[2];
    float* out = (float*)d_out;

    const int N = in_sizes[2];             // out_f = 4096
    const int K = in_sizes[1] / N;         // in_f  = 2048
    const int M = in_sizes[0] / K;         // batch = 4096

    short* xb = (short*)d_ws;
    short* wb = xb + in_sizes[0];
    // cvt also zeroes `out` (atomics accumulate across graph replays).
    cvt_kernel<<<2048, 256, 0, stream>>>(x, W, (short*)d_ws,
                                         (long)in_sizes[0], (long)in_sizes[1],
                                         out, out_size);

    dim3 grid(N / 256, M / 256);           // 256 blocks
    gemm_pool_kernel<<<grid, 512, 0, stream>>>(xb, wb, b, out, K);
}